// Round 6
// baseline (209.844 us; speedup 1.0000x reference)
//
#include <hip/hip_runtime.h>
#include <math.h>

#define B_  8
#define C_  64
#define H_  128
#define W_  128
#define KK_ 9
#define CO_ 64
#define HW_ (H_*W_)
#define CK_ 576

typedef __attribute__((ext_vector_type(8))) short bf16x8;
typedef __attribute__((ext_vector_type(4))) float f32x4;

__device__ inline float blo(unsigned u){ union{unsigned v;float f;}c; c.v = u<<16;          return c.f; }
__device__ inline float bhi(unsigned u){ union{unsigned v;float f;}c; c.v = u & 0xffff0000u; return c.f; }
__device__ inline unsigned short f2bf(float f){
    union{float f;unsigned u;} uu; uu.f = f;
    unsigned rr = uu.u + 0x7fffu + ((uu.u>>16)&1u);
    return (unsigned short)(rr >> 16);
}
// cheap pack: round-half-up + v_perm_b32 (3 VALU vs 7 for RNE)
__device__ inline unsigned packrn(float lo, float hi){
    union{float f;unsigned u;} a, b; a.f = lo; b.f = hi;
    return __builtin_amdgcn_perm(b.u + 0x8000u, a.u + 0x8000u, 0x07060302u);
}

// ---- prep_all: w_dcn -> w_bf[o][tap*64+c]; w_off -> wA[32][tap*64+c] ----
__global__ __launch_bounds__(256) void prep_all(
    const float* __restrict__ w_dcn, const float* __restrict__ w_off,
    unsigned short* __restrict__ w_bf, unsigned short* __restrict__ wA)
{
    int i = blockIdx.x * 256 + threadIdx.x;
    if (i < 64 * CK_) {
        int o = i / CK_, r = i % CK_;
        int tap = r >> 6, c = r & 63;
        w_bf[i] = f2bf(w_dcn[o * CK_ + c * 9 + tap]);
    } else {
        int j = i - 64 * CK_;                 // 0 .. 32*576-1
        int o = j / CK_, r = j % CK_;
        int tap = r >> 6, c = r & 63;
        float v = (o < 27) ? w_off[o * CK_ + c * 9 + tap] : 0.f;
        wA[j] = f2bf(v);
    }
}

// ---- transpose2: x NCHW fp32 -> xt NHWC bf16; px-major contiguous writes ---
__global__ __launch_bounds__(256) void transpose2(const float* __restrict__ x,
                                                  unsigned* __restrict__ xt)
{
    __shared__ float tb[64 * 65];
    int b = blockIdx.x >> 8;
    int pixbase = (blockIdx.x & 255) * 64;
    #pragma unroll
    for (int i = 0; i < 16; ++i) {
        int idx = i * 256 + threadIdx.x;
        int c = idx >> 6, pix = idx & 63;
        tb[c * 65 + pix] = x[((size_t)(b * C_ + c)) * HW_ + pixbase + pix];
    }
    __syncthreads();
    #pragma unroll
    for (int i = 0; i < 2; ++i) {
        int idx = i * 256 + threadIdx.x;      // 0..511
        int pix = idx >> 3, qd = idx & 7;     // qd = 16B quad (8 ch)
        uint4 v;
        v.x = packrn(tb[(qd*8+0)*65 + pix], tb[(qd*8+1)*65 + pix]);
        v.y = packrn(tb[(qd*8+2)*65 + pix], tb[(qd*8+3)*65 + pix]);
        v.z = packrn(tb[(qd*8+4)*65 + pix], tb[(qd*8+5)*65 + pix]);
        v.w = packrn(tb[(qd*8+6)*65 + pix], tb[(qd*8+7)*65 + pix]);
        *(uint4*)(xt + ((size_t)b * HW_ + pixbase + pix) * 32 + qd * 4) = v;
    }
}

// ---- dcn6: fused offset-conv (MFMA) + bilinear sample + dcn GEMM ----
// Block = 64 px x full problem. 4 waves.
#define SSTR4 400     // sS row stride bytes, 16B aligned
__global__ __launch_bounds__(256) void dcn6(
    const unsigned* __restrict__ xt,
    const unsigned short* __restrict__ wA,    // offset-conv weights [32][576]
    const float* __restrict__ b_off,
    const unsigned short* __restrict__ w_bf,  // dcn weights [64][576]
    float* __restrict__ out)
{
    __shared__ __align__(16) unsigned char sS[64 * SSTR4];  // 25.6 KB (aliases om)
    __shared__ float4 scr_w[576];
    __shared__ int    scr_o[576];
    float* om = (float*)sS;                   // [27][stride 65] conv outputs

    int tile = blockIdx.x;
    int b  = tile >> 8;
    int p0 = (tile & 255) * 64;
    int y  = p0 >> 7;
    int x0 = p0 & 127;                        // 0 or 64
    int t  = threadIdx.x;
    int lane = t & 63, w = t >> 6;
    int m = lane & 15, q = lane >> 4;

    const unsigned short* xbr = (const unsigned short*)(xt + (size_t)(b * HW_) * 32);

    // ================= Phase A: offset conv via MFMA =================
    {
        int o0c = (w & 1) * 16;               // conv o-tile
        int pxh = (w >> 1) * 32;              // conv px half (of 64-px tile)

        bf16x8 Ac[18];
        #pragma unroll
        for (int s = 0; s < 18; ++s)
            Ac[s] = *(const bf16x8*)(wA + (o0c + m) * CK_ + s * 32 + q * 8);

        f32x4 accc[2] = {};
        #pragma unroll
        for (int ky = 0; ky < 3; ++ky) {
            int yy = y + ky - 1;
            if (yy >= 0 && yy < H_) {
                const unsigned short* xr = xbr + (size_t)yy * W_ * 64;
                #pragma unroll
                for (int kx = 0; kx < 3; ++kx) {
                    #pragma unroll
                    for (int nt = 0; nt < 2; ++nt) {
                        int xbase = x0 + pxh + nt * 16;
                        int px = xbase + m + kx - 1;
                        bf16x8 b0, b1;
                        bool ledge = (xbase == 0   && kx == 0);
                        bool redge = (xbase == 112 && kx == 2);
                        if (ledge || redge) {
                            int pc = min(max(px, 0), W_ - 1);
                            const unsigned short* p = xr + pc * 64 + q * 8;
                            b0 = *(const bf16x8*)p;
                            b1 = *(const bf16x8*)(p + 32);
                            if (px != pc) {
                                b0 = (bf16x8){0,0,0,0,0,0,0,0};
                                b1 = (bf16x8){0,0,0,0,0,0,0,0};
                            }
                        } else {
                            const unsigned short* p = xr + px * 64 + q * 8;
                            b0 = *(const bf16x8*)p;
                            b1 = *(const bf16x8*)(p + 32);
                        }
                        int s2 = (ky * 3 + kx) * 2;
                        accc[nt] = __builtin_amdgcn_mfma_f32_16x16x32_bf16(Ac[s2],     b0, accc[nt], 0, 0, 0);
                        accc[nt] = __builtin_amdgcn_mfma_f32_16x16x32_bf16(Ac[s2 + 1], b1, accc[nt], 0, 0, 0);
                    }
                }
            }
        }
        // write conv outputs (biased, raw) to LDS om: col(px)=m, row(j)=q*4+r
        #pragma unroll
        for (int nt = 0; nt < 2; ++nt) {
            #pragma unroll
            for (int r = 0; r < 4; ++r) {
                int j = o0c + q * 4 + r;
                if (j < 27)
                    om[j * 65 + pxh + nt * 16 + m] = accc[nt][r] + b_off[j];
            }
        }
    }
    __syncthreads();

    // ================= Phase 0: offsets -> corner weights/offsets ===========
    for (int i = t; i < 576; i += 256) {
        int k = i >> 6, sp = i & 63;
        float dy = om[(2 * k)     * 65 + sp];
        float dx = om[(2 * k + 1) * 65 + sp];
        float mk = 1.f / (1.f + expf(-om[(18 + k) * 65 + sp]));
        float py = dy + (float)(y - 1 + k / 3);
        float px = dx + (float)(x0 + sp - 1 + k % 3);
        float fy = floorf(py), fx = floorf(px);
        int iy = (int)fy, ix = (int)fx;
        float ay = py - fy, ax = px - fx;
        float wy0 = (iy >= 0  && iy < H_)     ? (1.f - ay) : 0.f;
        float wy1 = (iy >= -1 && iy < H_ - 1) ? ay         : 0.f;
        float wx0 = (ix >= 0  && ix < W_)     ? (1.f - ax) : 0.f;
        float wx1 = (ix >= -1 && ix < W_ - 1) ? ax         : 0.f;
        int iy0 = min(max(iy, 0), H_ - 1);
        int iy1 = min(max(iy + 1, 0), H_ - 1);
        int ix0 = min(max(ix, 0), W_ - 1);
        int ix1 = min(max(ix + 1, 0), W_ - 1);
        scr_w[i] = make_float4(wy0*wx0*mk, wy0*wx1*mk, wy1*wx0*mk, wy1*wx1*mk);
        int off00 = (iy0 * W_ + ix0) * 128;
        scr_o[i] = off00 | ((ix1 != ix0) << 22) | ((iy1 != iy0) << 23);
    }

    // Preload dcn A-frags for this wave's 16 out-channels
    int o0 = w * 16;
    bf16x8 A[18];
    #pragma unroll
    for (int s = 0; s < 18; ++s)
        A[s] = *(const bf16x8*)(w_bf + (o0 + m) * CK_ + s * 32 + q * 8);

    __syncthreads();        // scr ready; om region (sS) now free

    // ================= Phase B: sampling + GEMM ==============================
    int cq = lane & 15;     // channel quad (4 ch = 2 dwords)
    int g  = lane >> 4;     // pixel-tap sub-index
    const unsigned char* xb = (const unsigned char*)xbr;
    f32x4 acc[4] = {};

    #pragma unroll
    for (int chunk = 0; chunk < 3; ++chunk) {
        const int tap0 = chunk * 3;
        for (int it = 0; it < 12; ++it) {
            int pi = (w * 12 + it) * 4 + g;   // 0..191
            int ktl = pi >> 6;
            int sp  = pi & 63;
            int idx = (tap0 + ktl) * 64 + sp;
            float4 w4 = scr_w[idx];
            int pk = scr_o[idx];
            int off00 = pk & 0x3FFFFF;
            int dxb = (pk >> 15) & 128;
            int dyb = (pk >> 9)  & 16384;
            const unsigned char* a00 = xb + off00 + cq * 8;
            uint2 u00 = *(const uint2*)(a00);
            uint2 u01 = *(const uint2*)(a00 + dxb);
            uint2 u10 = *(const uint2*)(a00 + dyb);
            uint2 u11 = *(const uint2*)(a00 + dyb + dxb);
            float l0 = w4.x*blo(u00.x) + w4.y*blo(u01.x) + w4.z*blo(u10.x) + w4.w*blo(u11.x);
            float h0 = w4.x*bhi(u00.x) + w4.y*bhi(u01.x) + w4.z*bhi(u10.x) + w4.w*bhi(u11.x);
            float l1 = w4.x*blo(u00.y) + w4.y*blo(u01.y) + w4.z*blo(u10.y) + w4.w*blo(u11.y);
            float h1 = w4.x*bhi(u00.y) + w4.y*bhi(u01.y) + w4.z*bhi(u10.y) + w4.w*bhi(u11.y);
            uint2 o2;
            o2.x = packrn(l0, h0);
            o2.y = packrn(l1, h1);
            *(uint2*)&sS[sp * SSTR4 + ktl * 128 + cq * 8] = o2;
        }
        __syncthreads();

        #pragma unroll
        for (int s = 0; s < 6; ++s) {
            #pragma unroll
            for (int nt = 0; nt < 4; ++nt) {
                bf16x8 bb = *(const bf16x8*)&sS[(nt * 16 + m) * SSTR4 + s * 64 + q * 16];
                acc[nt] = __builtin_amdgcn_mfma_f32_16x16x32_bf16(A[chunk * 6 + s], bb, acc[nt], 0, 0, 0);
            }
        }
        __syncthreads();
    }

    // Epilogue: col(px)=m, row(o)=q*4+reg
    #pragma unroll
    for (int nt = 0; nt < 4; ++nt) {
        #pragma unroll
        for (int r = 0; r < 4; ++r) {
            int o = o0 + q * 4 + r;
            out[((size_t)(b * CO_ + o)) * HW_ + p0 + nt * 16 + m] = acc[nt][r];
        }
    }
}

extern "C" void kernel_launch(void* const* d_in, const int* in_sizes, int n_in,
                              void* d_out, int out_size, void* d_ws, size_t ws_size,
                              hipStream_t stream)
{
    const float* x     = (const float*)d_in[0];
    const float* w_off = (const float*)d_in[1];
    const float* b_off = (const float*)d_in[2];
    const float* w_dcn = (const float*)d_in[3];
    float* out = (float*)d_out;

    unsigned* xt = (unsigned*)d_ws;                              // B*HW*32 dwords (16.8 MB)
    unsigned short* w_bf = (unsigned short*)(xt + (size_t)B_ * HW_ * 32);
    unsigned short* wA   = w_bf + 64 * CK_;

    prep_all<<<216, 256, 0, stream>>>(w_dcn, w_off, w_bf, wA);
    transpose2<<<B_ * 256, 256, 0, stream>>>(x, xt);
    dcn6<<<B_ * 256, 256, 0, stream>>>(xt, wA, b_off, w_bf, out);
}

// Round 8
// 194.248 us; speedup vs baseline: 1.0803x; 1.0803x over previous
//
#include <hip/hip_runtime.h>
#include <math.h>

#define B_  8
#define C_  64
#define H_  128
#define W_  128
#define KK_ 9
#define CO_ 64
#define HW_ (H_*W_)
#define CK_ 576

typedef _Float16 f16x8 __attribute__((ext_vector_type(8)));
typedef _Float16 h2    __attribute__((ext_vector_type(2)));
typedef __attribute__((ext_vector_type(4))) float f32x4;

__device__ inline unsigned pkrtz(float a, float b){
    auto v = __builtin_amdgcn_cvt_pkrtz(a, b);   // __fp16x2 on this toolchain
    union{decltype(v) h; unsigned u;} c; c.h = v; return c.u;
}
__device__ inline h2 u2h(unsigned u){ union{unsigned x; h2 h;} c; c.x = u; return c.h; }
__device__ inline unsigned h2u(h2 v){ union{h2 h; unsigned u;} c; c.h = v; return c.u; }
__device__ inline unsigned short f2h(float f){
    _Float16 h = (_Float16)f;
    union{_Float16 h; unsigned short s;} c; c.h = h; return c.s;
}

// ---- prep_all: w_dcn -> w_bf[o][tap*64+c] f16; w_off -> wA[32][tap*64+c] ----
__global__ __launch_bounds__(256) void prep_all(
    const float* __restrict__ w_dcn, const float* __restrict__ w_off,
    unsigned short* __restrict__ w_bf, unsigned short* __restrict__ wA)
{
    int i = blockIdx.x * 256 + threadIdx.x;
    if (i < 64 * CK_) {
        int o = i / CK_, r = i % CK_;
        int tap = r >> 6, c = r & 63;
        w_bf[i] = f2h(w_dcn[o * CK_ + c * 9 + tap]);
    } else {
        int j = i - 64 * CK_;                 // 0 .. 32*576-1
        int o = j / CK_, r = j % CK_;
        int tap = r >> 6, c = r & 63;
        float v = (o < 27) ? w_off[o * CK_ + c * 9 + tap] : 0.f;
        wA[j] = f2h(v);
    }
}

// ---- transpose3: x NCHW fp32 -> xt NHWC f16. Pack on LDS write. ----
__global__ __launch_bounds__(256) void transpose3(const float* __restrict__ x,
                                                  unsigned short* __restrict__ xt)
{
    __shared__ unsigned tb[64 * 33];          // [pix][ch-pair], stride 33: conflict-free
    int b = blockIdx.x >> 8;
    int pixbase = (blockIdx.x & 255) * 64;
    int t = threadIdx.x;
    #pragma unroll
    for (int i = 0; i < 8; ++i) {
        int idx = i * 256 + t;
        int cp = idx >> 6, pix = idx & 63;
        float f0 = x[((size_t)(b * C_) + 2 * cp    ) * HW_ + pixbase + pix];
        float f1 = x[((size_t)(b * C_) + 2 * cp + 1) * HW_ + pixbase + pix];
        tb[pix * 33 + cp] = pkrtz(f0, f1);
    }
    __syncthreads();
    unsigned* xo = (unsigned*)xt + ((size_t)b * HW_ + pixbase) * 32;
    #pragma unroll
    for (int i = 0; i < 2; ++i) {
        int idx = i * 256 + t;
        int pix = idx >> 3, j = idx & 7;
        uint4 v;
        v.x = tb[pix * 33 + j * 4 + 0];
        v.y = tb[pix * 33 + j * 4 + 1];
        v.z = tb[pix * 33 + j * 4 + 2];
        v.w = tb[pix * 33 + j * 4 + 3];
        *(uint4*)(xo + pix * 32 + j * 4) = v;   // contiguous 1KB per wave-instr
    }
}

// ---- dcn7: fused offset-conv (f16 MFMA) + packed-f16 sampling + dcn GEMM ----
#define SSTR4 400     // sS row stride bytes, 16B aligned
__global__ __launch_bounds__(256, 4) void dcn7(
    const unsigned short* __restrict__ xt,    // f16 NHWC
    const unsigned short* __restrict__ wA,    // offset-conv weights [32][576] f16
    const float* __restrict__ b_off,
    const unsigned short* __restrict__ w_bf,  // dcn weights [64][576] f16
    float* __restrict__ out)
{
    __shared__ __align__(16) unsigned char sS[64 * SSTR4];  // 25.6 KB (aliases om)
    __shared__ uint4 scr_w[576];              // dup-packed f16 corner weights
    __shared__ int   scr_o[576];              // packed corner offsets
    float* om = (float*)sS;                   // [27][stride 65] conv outputs

    int tile = blockIdx.x;
    int b  = tile >> 8;
    int p0 = (tile & 255) * 64;
    int y  = p0 >> 7;
    int x0 = p0 & 127;                        // 0 or 64
    int t  = threadIdx.x;
    int lane = t & 63, w = t >> 6;
    int m = lane & 15, q = lane >> 4;

    const unsigned short* xbr = xt + (size_t)(b * HW_) * 64;

    // ================= Phase A: offset conv via MFMA =================
    {
        int o0c = (w & 1) * 16;               // conv o-tile
        int pxh = (w >> 1) * 32;              // conv px half (of 64-px tile)

        f16x8 Ac[18];
        #pragma unroll
        for (int s = 0; s < 18; ++s)
            Ac[s] = *(const f16x8*)(wA + (o0c + m) * CK_ + s * 32 + q * 8);

        f32x4 accc[2] = {};
        #pragma unroll
        for (int ky = 0; ky < 3; ++ky) {
            int yy = y + ky - 1;
            if (yy >= 0 && yy < H_) {
                const unsigned short* xr = xbr + (size_t)yy * W_ * 64;
                #pragma unroll
                for (int kx = 0; kx < 3; ++kx) {
                    #pragma unroll
                    for (int nt = 0; nt < 2; ++nt) {
                        int xbase = x0 + pxh + nt * 16;
                        int px = xbase + m + kx - 1;
                        f16x8 b0, b1;
                        bool ledge = (xbase == 0   && kx == 0);
                        bool redge = (xbase == 112 && kx == 2);
                        if (ledge || redge) {
                            int pc = min(max(px, 0), W_ - 1);
                            const unsigned short* p = xr + pc * 64 + q * 8;
                            b0 = *(const f16x8*)p;
                            b1 = *(const f16x8*)(p + 32);
                            if (px != pc) {
                                b0 = (f16x8){0,0,0,0,0,0,0,0};
                                b1 = (f16x8){0,0,0,0,0,0,0,0};
                            }
                        } else {
                            const unsigned short* p = xr + px * 64 + q * 8;
                            b0 = *(const f16x8*)p;
                            b1 = *(const f16x8*)(p + 32);
                        }
                        int s2 = (ky * 3 + kx) * 2;
                        accc[nt] = __builtin_amdgcn_mfma_f32_16x16x32_f16(Ac[s2],     b0, accc[nt], 0, 0, 0);
                        accc[nt] = __builtin_amdgcn_mfma_f32_16x16x32_f16(Ac[s2 + 1], b1, accc[nt], 0, 0, 0);
                    }
                }
            }
        }
        #pragma unroll
        for (int nt = 0; nt < 2; ++nt) {
            #pragma unroll
            for (int r = 0; r < 4; ++r) {
                int j = o0c + q * 4 + r;
                if (j < 27)
                    om[j * 65 + pxh + nt * 16 + m] = accc[nt][r] + b_off[j];
            }
        }
    }
    __syncthreads();

    // ================= Phase 0: offsets -> dup-packed weights + offsets =====
    for (int i = t; i < 576; i += 256) {
        int k = i >> 6, sp = i & 63;
        float dy = om[(2 * k)     * 65 + sp];
        float dx = om[(2 * k + 1) * 65 + sp];
        float mk = 1.f / (1.f + __expf(-om[(18 + k) * 65 + sp]));
        float py = dy + (float)(y - 1 + k / 3);
        float px = dx + (float)(x0 + sp - 1 + k % 3);
        float fy = floorf(py), fx = floorf(px);
        int iy = (int)fy, ix = (int)fx;
        float ay = py - fy, ax = px - fx;
        float wy0 = (iy >= 0  && iy < H_)     ? (1.f - ay) : 0.f;
        float wy1 = (iy >= -1 && iy < H_ - 1) ? ay         : 0.f;
        float wx0 = (ix >= 0  && ix < W_)     ? (1.f - ax) : 0.f;
        float wx1 = (ix >= -1 && ix < W_ - 1) ? ax         : 0.f;
        int iy0 = min(max(iy, 0), H_ - 1);
        int iy1 = min(max(iy + 1, 0), H_ - 1);
        int ix0 = min(max(ix, 0), W_ - 1);
        int ix1 = min(max(ix + 1, 0), W_ - 1);
        float w00 = wy0*wx0*mk, w01 = wy0*wx1*mk, w10 = wy1*wx0*mk, w11 = wy1*wx1*mk;
        uint4 wv;
        wv.x = pkrtz(w00, w00); wv.y = pkrtz(w01, w01);
        wv.z = pkrtz(w10, w10); wv.w = pkrtz(w11, w11);
        scr_w[i] = wv;
        int off00 = (iy0 * W_ + ix0) * 128;   // bytes (64ch * 2B f16)
        scr_o[i] = off00 | ((ix1 != ix0) << 22) | ((iy1 != iy0) << 23);
    }

    // Preload dcn A-frags for this wave's 16 out-channels
    int o0 = w * 16;
    f16x8 A[18];
    #pragma unroll
    for (int s = 0; s < 18; ++s)
        A[s] = *(const f16x8*)(w_bf + (o0 + m) * CK_ + s * 32 + q * 8);

    __syncthreads();        // scr ready; om region (sS) now free

    // ================= Phase B: pipelined sampling + GEMM ====================
    int cq = lane & 15;     // channel quad (4 ch = 2 dwords)
    int g  = lane >> 4;     // pixel-tap sub-index
    const unsigned char* xb = (const unsigned char*)xbr;
    f32x4 acc[4] = {};
    int piB = w * 48 + g;

    #pragma unroll
    for (int chunk = 0; chunk < 3; ++chunk) {
        const int tap0 = chunk * 3;
        // prologue: scr for it0,it1; corners for it0
        uint4 wqA, wqB; int pkB;
        uint2 a00, a01, a10, a11;
        {
            int pi = piB;
            int idx = (tap0 + (pi >> 6)) * 64 + (pi & 63);
            wqA = scr_w[idx]; int pkA = scr_o[idx];
            int pi2 = piB + 4;
            int idx2 = (tap0 + (pi2 >> 6)) * 64 + (pi2 & 63);
            wqB = scr_w[idx2]; pkB = scr_o[idx2];
            const unsigned char* a0 = xb + (pkA & 0x3FFFFF) + cq * 8;
            int dxb = (pkA >> 15) & 128;
            int dyb = (pkA >> 9)  & 16384;
            a00 = *(const uint2*)(a0);
            a01 = *(const uint2*)(a0 + dxb);
            a10 = *(const uint2*)(a0 + dyb);
            a11 = *(const uint2*)(a0 + dyb + dxb);
        }
        #pragma unroll
        for (int it = 0; it < 12; ++it) {
            uint4 wqC = {}; int pkC = 0;
            if (it < 10) {
                int pi = piB + 4 * (it + 2);
                int idx = (tap0 + (pi >> 6)) * 64 + (pi & 63);
                wqC = scr_w[idx]; pkC = scr_o[idx];
            }
            uint2 n00 = {}, n01 = {}, n10 = {}, n11 = {};
            if (it < 11) {
                const unsigned char* a0 = xb + (pkB & 0x3FFFFF) + cq * 8;
                int dxb = (pkB >> 15) & 128;
                int dyb = (pkB >> 9)  & 16384;
                n00 = *(const uint2*)(a0);
                n01 = *(const uint2*)(a0 + dxb);
                n10 = *(const uint2*)(a0 + dyb);
                n11 = *(const uint2*)(a0 + dyb + dxb);
            }
            // blend current iter in packed f16
            h2 r0 = u2h(wqA.x) * u2h(a00.x) + u2h(wqA.y) * u2h(a01.x)
                  + u2h(wqA.z) * u2h(a10.x) + u2h(wqA.w) * u2h(a11.x);
            h2 r1 = u2h(wqA.x) * u2h(a00.y) + u2h(wqA.y) * u2h(a01.y)
                  + u2h(wqA.z) * u2h(a10.y) + u2h(wqA.w) * u2h(a11.y);
            int pi = piB + 4 * it;
            int ktl = pi >> 6, sp = pi & 63;
            uint2 o2; o2.x = h2u(r0); o2.y = h2u(r1);
            *(uint2*)&sS[sp * SSTR4 + ktl * 128 + cq * 8] = o2;
            wqA = wqB; wqB = wqC; pkB = pkC;
            a00 = n00; a01 = n01; a10 = n10; a11 = n11;
        }
        __syncthreads();

        #pragma unroll
        for (int s = 0; s < 6; ++s) {
            #pragma unroll
            for (int nt = 0; nt < 4; ++nt) {
                f16x8 bb = *(const f16x8*)&sS[(nt * 16 + m) * SSTR4 + s * 64 + q * 16];
                acc[nt] = __builtin_amdgcn_mfma_f32_16x16x32_f16(A[chunk * 6 + s], bb, acc[nt], 0, 0, 0);
            }
        }
        __syncthreads();
    }

    // Epilogue: col(px)=m, row(o)=q*4+reg
    #pragma unroll
    for (int nt = 0; nt < 4; ++nt) {
        #pragma unroll
        for (int r = 0; r < 4; ++r) {
            int o = o0 + q * 4 + r;
            out[((size_t)(b * CO_ + o)) * HW_ + p0 + nt * 16 + m] = acc[nt][r];
        }
    }
}

extern "C" void kernel_launch(void* const* d_in, const int* in_sizes, int n_in,
                              void* d_out, int out_size, void* d_ws, size_t ws_size,
                              hipStream_t stream)
{
    const float* x     = (const float*)d_in[0];
    const float* w_off = (const float*)d_in[1];
    const float* b_off = (const float*)d_in[2];
    const float* w_dcn = (const float*)d_in[3];
    float* out = (float*)d_out;

    unsigned short* xt   = (unsigned short*)d_ws;                // B*HW*64 f16 (8.4 MB)
    unsigned short* w_bf = xt + (size_t)B_ * HW_ * 64;
    unsigned short* wA   = w_bf + 64 * CK_;

    prep_all<<<216, 256, 0, stream>>>(w_dcn, w_off, w_bf, wA);
    transpose3<<<B_ * 256, 256, 0, stream>>>(x, xt);
    dcn7<<<B_ * 256, 256, 0, stream>>>(xt, wA, b_off, w_bf, out);
}